// Round 9
// baseline (843.137 us; speedup 1.0000x reference)
//
#include <hip/hip_runtime.h>
#include <hip/hip_bf16.h>

// Hopfield forward. ROUND 9 = ABLATION ROUND: 5 sweep variants as separate
// dispatches; rocprof per-dispatch dur_us decomposes the 211us sweep.
// V0=full(real output, launched last), V1=no chain, V2=no K loads,
// V3=phase1 stub, V4=phase3 stub. V1..V4 write scratch sbits.

#define OFF_COLB   0u                       // u64 [8][4096]  colbitsP (bits over l)
#define OFF_XBITS  (256u<<10)               // u64 [512][64]  row bits (bits over i)
#define OFF_XBW    (512u<<10)               // u64 [64][512]  xbitsW (i-block major)
#define OFF_KF     (768u<<10)               // f32 [64][64][64] Kf : 1 MB
#define OFF_BCORR  (1792u<<10)              // f32 [4096] baseCorr
#define OFF_U      (1808u<<10)              // f32 [64][512] U
#define OFF_CST    (1936u<<10)              // float4 [4096] {f, A, dp, c}
#define OFF_P0     (2000u<<10)              // f32 [512]
#define OFF_SBITS  (2002u<<10)              // u64 [64]
#define OFF_CNT    (2003u<<10)              // int [4096]
#define OFF_HDR    (2019u<<10)              // f32 [16]  (rho)
#define OFF_BS0    (2020u<<10)              // f32 [64] blkS0
#define OFF_BS0C   (2021u<<10)              // f32 [64] blkS0C
#define OFF_SCR    (2022u<<10)              // u64 [4][64] scratch sbits for V1..V4

template<int CTRL, int RMASK>
__device__ __forceinline__ float dpp_add(float x){
  int t = __builtin_amdgcn_update_dpp(0, __float_as_int(x), CTRL, RMASK, 0xf, true);
  return x + __int_as_float(t);
}
__device__ __forceinline__ float wave_allsum(float x){
  x = dpp_add<0x111,0xf>(x);
  x = dpp_add<0x112,0xf>(x);
  x = dpp_add<0x114,0xf>(x);
  x = dpp_add<0x118,0xf>(x);
  x = dpp_add<0x142,0xa>(x);
  x = dpp_add<0x143,0xc>(x);
  return __int_as_float(__builtin_amdgcn_readlane(__float_as_int(x), 63));
}

// ---- row bits + transposed-block layout
__global__ void k_xbits(const float* __restrict__ llv, unsigned long long* __restrict__ xbits,
                        unsigned long long* __restrict__ xbitsW){
  int w = threadIdx.x >> 6, lane = threadIdx.x & 63;
  int l = blockIdx.x*4 + w;
  unsigned long long myword = 0;
  for (int c = 0; c < 64; ++c){
    float v = llv[(size_t)l*4096 + c*64 + lane];
    unsigned long long b = __ballot(v >= 0.0f);
    if (c == lane) myword = b;
  }
  xbits[(size_t)l*64 + lane] = myword;
  xbitsW[(size_t)lane*512 + l] = myword;
}

// ---- bit transpose
__global__ void k_bitT(const unsigned long long* __restrict__ xbits,
                       unsigned long long* __restrict__ colbitsP){
  int li = blockIdx.x;   // 0..7
  int ii = blockIdx.y;   // 0..63
  int lane = threadIdx.x;
  unsigned long long w = xbits[(size_t)(li*64 + lane)*64 + ii];
  unsigned long long myw = 0;
  for (int j = 0; j < 64; ++j){
    unsigned long long b = __ballot((w >> j) & 1ull);
    if (j == lane) myw = b;
  }
  colbitsP[(size_t)li*4096 + ii*64 + lane] = myw;
}

// ---- column positive counts
__global__ void k_colc(const unsigned long long* __restrict__ colbitsP, int* __restrict__ colcnt){
  int i = blockIdx.x*256 + threadIdx.x;
  int c = 0;
  #pragma unroll
  for (int wl = 0; wl < 8; ++wl) c += __popcll(colbitsP[(size_t)wl*4096 + i]);
  colcnt[i] = c;
}

// ---- rho (exact integer)
__global__ void k_rho(const int* __restrict__ colcnt, float* __restrict__ hdr){
  __shared__ int sh[256];
  int tid = threadIdx.x;
  int s = 0;
  for (int k = tid; k < 4096; k += 256) s += colcnt[k];
  sh[tid] = s; __syncthreads();
  for (int st = 128; st > 0; st >>= 1){
    if (tid < st) sh[tid] += sh[tid + st];
    __syncthreads();
  }
  if (tid == 0){
    int num = 2*sh[0] - 2097152;
    hdr[0] = (float)num * (1.0f/2097152.0f);
  }
}

// ---- per-step constants {f, A, dp, c}
__global__ void k_const(const int* __restrict__ colcnt, const float* __restrict__ hdr,
                        const float* __restrict__ s0, float4* __restrict__ cst){
  int i = blockIdx.x*256 + threadIdx.x;
  float rho = hdr[0];
  float c  = (float)(2*colcnt[i] - 512);
  float r2 = rho*rho;
  float q  = 512.0f + 512.0f*r2 - 2.0f*rho*c;
  float s  = s0[i];
  float4 o;
  o.x = q * s;
  o.y = rho*c - 512.0f*r2;
  o.z = 1.0f - s;
  o.w = c;
  cst[i] = o;
}

// ---- diagonal K blocks + baseCorr + block s0 sums
__global__ void k_kdiag(const unsigned long long* __restrict__ colbitsP,
                        const float4* __restrict__ cst, const float* __restrict__ s0,
                        const float* __restrict__ hdr,
                        float* __restrict__ Kf, float* __restrict__ baseCorr,
                        float* __restrict__ blkS0, float* __restrict__ blkS0C){
  __shared__ unsigned long long cb[8][64];
  __shared__ float Kl[64][64];
  __shared__ float cs[64], ss[64];
  int b = blockIdx.x, i0 = b*64, tid = threadIdx.x;  // 256 threads
  for (int k = tid; k < 512; k += 256)
    cb[k>>6][k&63] = colbitsP[(size_t)(k>>6)*4096 + i0 + (k&63)];
  if (tid < 64){ cs[tid] = cst[i0+tid].w; ss[tid] = s0[i0+tid]; }
  __syncthreads();
  float rho = hdr[0];
  float r2t = 512.0f*rho*rho;
  #pragma unroll
  for (int k = 0; k < 16; ++k){
    int q = tid*16 + k;
    int t = q >> 6, j = q & 63;
    int acc = 0;
    #pragma unroll
    for (int wl = 0; wl < 8; ++wl) acc += __popcll(cb[wl][t] ^ cb[wl][j]);
    float G = (float)(512 - 2*acc);
    float kf = G - rho*(cs[t]+cs[j]) + r2t;
    Kl[t][j] = kf;
    Kf[(size_t)b*4096 + q] = kf;
  }
  __syncthreads();
  if (tid < 64){
    float bc = 0.0f;
    for (int j = 0; j < tid; ++j) bc = fmaf(ss[j], Kl[tid][j], bc);
    baseCorr[i0 + tid] = bc;
  }
  if (tid == 64){
    float a = 0.0f, b2 = 0.0f;
    for (int j = 0; j < 64; ++j){ a += ss[j]; b2 = fmaf(ss[j], cs[j], b2); }
    blkS0[b] = a; blkS0C[b] = b2;
  }
}

// ---- U[b][l] = sum_j s0[i0+j] * x[l][i0+j]
__global__ void k_u(const unsigned long long* __restrict__ xbits, const float* __restrict__ s0,
                    float* __restrict__ U){
  __shared__ float s0l[64];
  int b = blockIdx.x, l = threadIdx.x;  // 512 threads
  if (l < 64) s0l[l] = s0[b*64 + l];
  __syncthreads();
  unsigned long long w = xbits[(size_t)l*64 + b];
  unsigned int lo = (unsigned)w, hi = (unsigned)(w >> 32);
  unsigned int nlo = ~lo, nhi = ~hi;
  float acc = 0.0f;
  #pragma unroll
  for (int j = 0; j < 32; ++j){
    unsigned int m = (nlo << (31-j)) & 0x80000000u;
    acc += __uint_as_float(__float_as_uint(s0l[j]) ^ m);
  }
  #pragma unroll
  for (int j = 0; j < 32; ++j){
    unsigned int m = (nhi << (31-j)) & 0x80000000u;
    acc += __uint_as_float(__float_as_uint(s0l[32+j]) ^ m);
  }
  U[(size_t)b*512 + l] = acc;
}

// ---- p0[l] = sum_j sign(llv[l,j]) * s0[j]
__global__ void k_pinit(const float* __restrict__ llv, const float* __restrict__ s0,
                        float* __restrict__ p0){
  int l = blockIdx.x, lane = threadIdx.x;
  float acc = 0.0f;
  for (int c = 0; c < 64; ++c){
    float v = llv[(size_t)l*4096 + c*64 + lane];
    float sg = (v >= 0.0f) ? 1.0f : -1.0f;
    acc = fmaf(sg, s0[c*64 + lane], acc);
  }
  float tot = wave_allsum(acc);
  if (lane == 0) p0[l] = tot;
}

// ---- K row loads + scalar pins
#define K_DECL(P) float4 P##0,P##1,P##2,P##3,P##4,P##5,P##6,P##7,P##8,P##9,P##10,P##11,P##12,P##13,P##14,P##15;
#define K_LOAD(P, BIDX) { const float4* kp_ = (const float4*)(Kf + (size_t)(BIDX)*4096 + t*64); \
  P##0=kp_[0];  P##1=kp_[1];  P##2=kp_[2];  P##3=kp_[3];  \
  P##4=kp_[4];  P##5=kp_[5];  P##6=kp_[6];  P##7=kp_[7];  \
  P##8=kp_[8];  P##9=kp_[9];  P##10=kp_[10];P##11=kp_[11];\
  P##12=kp_[12];P##13=kp_[13];P##14=kp_[14];P##15=kp_[15]; }
#define PINF(X) asm volatile("" : "+v"(X))
#define PIN4(Q) { PINF(Q.x); PINF(Q.y); PINF(Q.z); PINF(Q.w); }
#define K_PIN(P) { PIN4(P##0); PIN4(P##1); PIN4(P##2); PIN4(P##3); \
  PIN4(P##4); PIN4(P##5); PIN4(P##6); PIN4(P##7); \
  PIN4(P##8); PIN4(P##9); PIN4(P##10); PIN4(P##11); \
  PIN4(P##12); PIN4(P##13); PIN4(P##14); PIN4(P##15); }

// serial step
#define STP(KVAL, J) { \
  int vi_ = __builtin_amdgcn_readlane(__float_as_int(v), (J)); \
  float sg2_ = (vi_ < 0) ? -1.0f : 1.0f; \
  sg_ |= ((unsigned long long)((~((unsigned)vi_)) >> 31)) << (J); \
  v = fmaf(sg2_, (KVAL), v); }
#define STP4(Q, J0) STP(Q.x,(J0)+0) STP(Q.y,(J0)+1) STP(Q.z,(J0)+2) STP(Q.w,(J0)+3)
#define PH2(P) STP4(P##0,0)  STP4(P##1,4)  STP4(P##2,8)  STP4(P##3,12) \
               STP4(P##4,16) STP4(P##5,20) STP4(P##6,24) STP4(P##7,28) \
               STP4(P##8,32) STP4(P##9,36) STP4(P##10,40) STP4(P##11,44) \
               STP4(P##12,48) STP4(P##13,52) STP4(P##14,56) STP4(P##15,60)
// literal-K chain (V2): same chain structure, inline-const operand
#define STPL4(J0) STP(2.0f,(J0)+0) STP(2.0f,(J0)+1) STP(2.0f,(J0)+2) STP(2.0f,(J0)+3)
#define PH2LIT STPL4(0) STPL4(4) STPL4(8) STPL4(12) STPL4(16) STPL4(20) STPL4(24) STPL4(28) \
               STPL4(32) STPL4(36) STPL4(40) STPL4(44) STPL4(48) STPL4(52) STPL4(56) STPL4(60)

// ---- the blocked sequential sweep, template-ablated.
// V: 0=full 1=no-chain 2=no-K-loads 3=phase1-stub 4=phase3-stub
template<int V>
__global__ __launch_bounds__(512, 1)
void k_sweepT(const unsigned long long* __restrict__ colbitsP,
              const unsigned long long* __restrict__ xbitsW,
              const float* __restrict__ Kf, const float* __restrict__ baseCorr,
              const float* __restrict__ blkS0, const float* __restrict__ blkS0C,
              const float* __restrict__ U, const float4* __restrict__ cst,
              const float* __restrict__ p0, const float* __restrict__ s0,
              const float* __restrict__ hdr, unsigned long long* __restrict__ sbits)
{
  __shared__ float p[512];
  __shared__ float part[8][64];
  __shared__ float red[512];
  __shared__ unsigned long long sig;
  int tid = threadIdx.x, g = tid >> 6, t = tid & 63;
  float rho = hdr[0];

  // init p, P, T
  p[tid] = p0[tid];
  red[tid] = p0[tid];
  __syncthreads();
  for (int st = 256; st > 0; st >>= 1){ if (tid < st) red[tid] += red[tid+st]; __syncthreads(); }
  float Preg = red[0];
  __syncthreads();
  { float a = 0.0f; for (int k = 0; k < 8; ++k) a += s0[tid*8 + k]; red[tid] = a; }
  __syncthreads();
  for (int st = 256; st > 0; st >>= 1){ if (tid < st) red[tid] += red[tid+st]; __syncthreads(); }
  float Treg = red[0];
  __syncthreads();

  K_DECL(KA)

  for (int b = 0; b < 64; ++b){
    int i0 = b*64;
    // hoisted pure loads
    unsigned long long xw_ = 0ull; float uu_ = 0.0f;
    if (V != 4){ xw_ = xbitsW[(size_t)b*512 + tid]; uu_ = U[(size_t)b*512 + tid]; }
    float4 cc = make_float4(0.f,0.f,0.f,0.f);
    float bc_ = 0.0f, bs0_ = 0.0f, bsc_ = 0.0f;
    if (g == 0){
      if (V != 2){ K_LOAD(KA, b); }
      cc   = cst[i0 + t];
      bc_  = baseCorr[i0 + t];
      bs0_ = blkS0[b];
      bsc_ = blkS0C[b];
    }
    // phase 1
    if (V != 3){
      unsigned long long w = colbitsP[(size_t)g*4096 + i0 + t];
      unsigned int lo = (unsigned)w, hi = (unsigned)(w >> 32);
      unsigned int nlo = ~lo, nhi = ~hi;
      float acc = 0.0f;
      #pragma unroll
      for (int j = 0; j < 32; ++j){
        unsigned int m = (nlo << (31-j)) & 0x80000000u;
        acc += __uint_as_float(__float_as_uint(p[g*64 + j]) ^ m);
      }
      #pragma unroll
      for (int j = 0; j < 32; ++j){
        unsigned int m = (nhi << (31-j)) & 0x80000000u;
        acc += __uint_as_float(__float_as_uint(p[g*64 + 32 + j]) ^ m);
      }
      part[g][t] = acc;
    } else {
      part[g][t] = p[g*64 + t];    // stub: 1 LDS read
    }
    if (g == 0 && V != 2){ K_PIN(KA) }
    __syncthreads();              // B1

    if (g == 0){
      float S = 0.0f;
      #pragma unroll
      for (int gg = 0; gg < 8; ++gg) S += part[gg][t];
      float v = S - cc.x - rho*Preg - cc.y*Treg - bc_;
      unsigned long long sg_ = 0ull;
      if (V == 1){
        sg_ = 0xAAAAAAAAAAAAAAAAull;   // no chain; K kept alive by pins above
        asm volatile("" :: "v"(v));    // keep v computation live
      } else if (V == 2){
        PH2LIT;                        // chain with inline-const K
      } else {
        PH2(KA);                       // full chain
      }
      if (t == 0){ sig = sg_; sbits[b] = sg_; }
      float sv = ((sg_ >> t) & 1ull) ? cc.w : -cc.w;
      float sc = wave_allsum(sv);
      int pcs = __popcll(sg_);
      Preg += sc - bsc_;
      Treg += (float)(2*pcs - 64) - bs0_;
    }
    __syncthreads();              // B2
    // phase 3
    if (V != 4){
      unsigned long long sgv = sig;
      int pc = __popcll(xw_ ^ sgv);
      p[tid] = p[tid] + (float)(64 - 2*pc) - uu_;
    } else {
      p[tid] = p[tid] + 1.0f;     // stub
    }
    __syncthreads();              // B3
  }
}

// ---- exact integer scores + argmax one-hot
__global__ void k_scores(const unsigned long long* __restrict__ xbits,
                         const unsigned long long* __restrict__ sbits,
                         float* __restrict__ out){
  __shared__ unsigned long long sb[64];
  __shared__ int bestkey;
  int tid = threadIdx.x;  // 512
  if (tid < 64) sb[tid] = sbits[tid];
  if (tid == 0) bestkey = -1;
  __syncthreads();
  int acc = 0;
  #pragma unroll
  for (int w = 0; w < 64; ++w)
    acc += __popcll(xbits[(size_t)tid*64 + w] ^ sb[w]);
  int dot = 4096 - 2*acc;
  int ad  = dot < 0 ? -dot : dot;
  int key = (ad << 10) | (511 - tid);
  atomicMax(&bestkey, key);
  __syncthreads();
  int bl = 511 - (bestkey & 1023);
  float val = (float)(bestkey >> 10) * (1.0f/4096.0f);
  out[tid] = (tid == bl) ? val : 0.0f;
}

extern "C" void kernel_launch(void* const* d_in, const int* in_sizes, int n_in,
                              void* d_out, int out_size, void* d_ws, size_t ws_size,
                              hipStream_t stream){
  const float* s0  = (const float*)d_in[0];   // [4096]
  const float* llv = (const float*)d_in[1];   // [512][4096]
  float* out = (float*)d_out;                 // [512]
  char* ws = (char*)d_ws;

  unsigned long long* colbitsP = (unsigned long long*)(ws + OFF_COLB);
  unsigned long long* xbits    = (unsigned long long*)(ws + OFF_XBITS);
  unsigned long long* xbitsW   = (unsigned long long*)(ws + OFF_XBW);
  float*  Kf    = (float*)(ws + OFF_KF);
  float*  bcorr = (float*)(ws + OFF_BCORR);
  float*  U     = (float*)(ws + OFF_U);
  float4* cst   = (float4*)(ws + OFF_CST);
  float*  p0    = (float*)(ws + OFF_P0);
  unsigned long long* sbits = (unsigned long long*)(ws + OFF_SBITS);
  int*    colcnt = (int*)(ws + OFF_CNT);
  float*  hdr   = (float*)(ws + OFF_HDR);
  float*  bS0   = (float*)(ws + OFF_BS0);
  float*  bS0C  = (float*)(ws + OFF_BS0C);
  unsigned long long* scr = (unsigned long long*)(ws + OFF_SCR);

  k_xbits<<<128, 256, 0, stream>>>(llv, xbits, xbitsW);
  k_bitT<<<dim3(8, 64), 64, 0, stream>>>(xbits, colbitsP);
  k_colc<<<16, 256, 0, stream>>>(colbitsP, colcnt);
  k_rho<<<1, 256, 0, stream>>>(colcnt, hdr);
  k_const<<<16, 256, 0, stream>>>(colcnt, hdr, s0, cst);
  k_kdiag<<<64, 256, 0, stream>>>(colbitsP, cst, s0, hdr, Kf, bcorr, bS0, bS0C);
  k_u<<<64, 512, 0, stream>>>(xbits, s0, U);
  k_pinit<<<512, 64, 0, stream>>>(llv, s0, p0);

  // ablation dispatches (scratch outputs), then the real one
  k_sweepT<1><<<1, 512, 0, stream>>>(colbitsP, xbitsW, Kf, bcorr, bS0, bS0C, U, cst, p0, s0, hdr, scr + 0*64);
  k_sweepT<2><<<1, 512, 0, stream>>>(colbitsP, xbitsW, Kf, bcorr, bS0, bS0C, U, cst, p0, s0, hdr, scr + 1*64);
  k_sweepT<3><<<1, 512, 0, stream>>>(colbitsP, xbitsW, Kf, bcorr, bS0, bS0C, U, cst, p0, s0, hdr, scr + 2*64);
  k_sweepT<4><<<1, 512, 0, stream>>>(colbitsP, xbitsW, Kf, bcorr, bS0, bS0C, U, cst, p0, s0, hdr, scr + 3*64);
  k_sweepT<0><<<1, 512, 0, stream>>>(colbitsP, xbitsW, Kf, bcorr, bS0, bS0C, U, cst, p0, s0, hdr, sbits);

  k_scores<<<1, 512, 0, stream>>>(xbits, sbits, out);
}

// Round 10
// 220.138 us; speedup vs baseline: 3.8300x; 3.8300x over previous
//
#include <hip/hip_runtime.h>
#include <hip/hip_bf16.h>

// Hopfield forward, blocked factored Gauss-Seidel.
// Round 10: steady-state loop is LDS/register-only. Per 2-block group, stage
// K/colbits/xbits/U/cst/bcorr into LDS (coalesced bulk copy, 1 barrier), then
// all three phases run from LDS. K stored with f^(row&15) float4 swizzle
// (kills stride-256B bank conflicts); chain reads K via ping-pong b128 chunks.

#define OFF_COLB   0u                       // u64 [8][4096]  colbitsP (bits over l)
#define OFF_XBITS  (256u<<10)               // u64 [512][64]  row bits (bits over i)
#define OFF_XBW    (512u<<10)               // u64 [64][512]  xbitsW (i-block major)
#define OFF_KF     (768u<<10)               // f32 [64][64][64] Kf : 1 MB
#define OFF_BCORR  (1792u<<10)              // f32 [4096] baseCorr
#define OFF_U      (1808u<<10)               // f32 [64][512] U
#define OFF_CST    (1936u<<10)              // float4 [4096] {f, A, dp, c}
#define OFF_P0     (2000u<<10)              // f32 [512]
#define OFF_SBITS  (2002u<<10)              // u64 [64]
#define OFF_CNT    (2003u<<10)              // int [4096]
#define OFF_HDR    (2019u<<10)              // f32 [16]  (rho)
#define OFF_BS0    (2020u<<10)              // f32 [64] blkS0
#define OFF_BS0C   (2021u<<10)              // f32 [64] blkS0C

template<int CTRL, int RMASK>
__device__ __forceinline__ float dpp_add(float x){
  int t = __builtin_amdgcn_update_dpp(0, __float_as_int(x), CTRL, RMASK, 0xf, true);
  return x + __int_as_float(t);
}
__device__ __forceinline__ float wave_allsum(float x){
  x = dpp_add<0x111,0xf>(x);
  x = dpp_add<0x112,0xf>(x);
  x = dpp_add<0x114,0xf>(x);
  x = dpp_add<0x118,0xf>(x);
  x = dpp_add<0x142,0xa>(x);
  x = dpp_add<0x143,0xc>(x);
  return __int_as_float(__builtin_amdgcn_readlane(__float_as_int(x), 63));
}

// ---- row bits + transposed-block layout
__global__ void k_xbits(const float* __restrict__ llv, unsigned long long* __restrict__ xbits,
                        unsigned long long* __restrict__ xbitsW){
  int w = threadIdx.x >> 6, lane = threadIdx.x & 63;
  int l = blockIdx.x*4 + w;
  unsigned long long myword = 0;
  for (int c = 0; c < 64; ++c){
    float v = llv[(size_t)l*4096 + c*64 + lane];
    unsigned long long b = __ballot(v >= 0.0f);
    if (c == lane) myword = b;
  }
  xbits[(size_t)l*64 + lane] = myword;
  xbitsW[(size_t)lane*512 + l] = myword;
}

// ---- bit transpose
__global__ void k_bitT(const unsigned long long* __restrict__ xbits,
                       unsigned long long* __restrict__ colbitsP){
  int li = blockIdx.x;   // 0..7
  int ii = blockIdx.y;   // 0..63
  int lane = threadIdx.x;
  unsigned long long w = xbits[(size_t)(li*64 + lane)*64 + ii];
  unsigned long long myw = 0;
  for (int j = 0; j < 64; ++j){
    unsigned long long b = __ballot((w >> j) & 1ull);
    if (j == lane) myw = b;
  }
  colbitsP[(size_t)li*4096 + ii*64 + lane] = myw;
}

// ---- column positive counts
__global__ void k_colc(const unsigned long long* __restrict__ colbitsP, int* __restrict__ colcnt){
  int i = blockIdx.x*256 + threadIdx.x;
  int c = 0;
  #pragma unroll
  for (int wl = 0; wl < 8; ++wl) c += __popcll(colbitsP[(size_t)wl*4096 + i]);
  colcnt[i] = c;
}

// ---- rho (exact integer)
__global__ void k_rho(const int* __restrict__ colcnt, float* __restrict__ hdr){
  __shared__ int sh[256];
  int tid = threadIdx.x;
  int s = 0;
  for (int k = tid; k < 4096; k += 256) s += colcnt[k];
  sh[tid] = s; __syncthreads();
  for (int st = 128; st > 0; st >>= 1){
    if (tid < st) sh[tid] += sh[tid + st];
    __syncthreads();
  }
  if (tid == 0){
    int num = 2*sh[0] - 2097152;
    hdr[0] = (float)num * (1.0f/2097152.0f);
  }
}

// ---- per-step constants {f, A, dp, c}
__global__ void k_const(const int* __restrict__ colcnt, const float* __restrict__ hdr,
                        const float* __restrict__ s0, float4* __restrict__ cst){
  int i = blockIdx.x*256 + threadIdx.x;
  float rho = hdr[0];
  float c  = (float)(2*colcnt[i] - 512);
  float r2 = rho*rho;
  float q  = 512.0f + 512.0f*r2 - 2.0f*rho*c;
  float s  = s0[i];
  float4 o;
  o.x = q * s;
  o.y = rho*c - 512.0f*r2;
  o.z = 1.0f - s;
  o.w = c;
  cst[i] = o;
}

// ---- diagonal K blocks + baseCorr + block s0 sums
__global__ void k_kdiag(const unsigned long long* __restrict__ colbitsP,
                        const float4* __restrict__ cst, const float* __restrict__ s0,
                        const float* __restrict__ hdr,
                        float* __restrict__ Kf, float* __restrict__ baseCorr,
                        float* __restrict__ blkS0, float* __restrict__ blkS0C){
  __shared__ unsigned long long cb[8][64];
  __shared__ float Kl[64][64];
  __shared__ float cs[64], ss[64];
  int b = blockIdx.x, i0 = b*64, tid = threadIdx.x;  // 256 threads
  for (int k = tid; k < 512; k += 256)
    cb[k>>6][k&63] = colbitsP[(size_t)(k>>6)*4096 + i0 + (k&63)];
  if (tid < 64){ cs[tid] = cst[i0+tid].w; ss[tid] = s0[i0+tid]; }
  __syncthreads();
  float rho = hdr[0];
  float r2t = 512.0f*rho*rho;
  #pragma unroll
  for (int k = 0; k < 16; ++k){
    int q = tid*16 + k;
    int t = q >> 6, j = q & 63;
    int acc = 0;
    #pragma unroll
    for (int wl = 0; wl < 8; ++wl) acc += __popcll(cb[wl][t] ^ cb[wl][j]);
    float G = (float)(512 - 2*acc);
    float kf = G - rho*(cs[t]+cs[j]) + r2t;
    Kl[t][j] = kf;
    Kf[(size_t)b*4096 + q] = kf;
  }
  __syncthreads();
  if (tid < 64){
    float bc = 0.0f;
    for (int j = 0; j < tid; ++j) bc = fmaf(ss[j], Kl[tid][j], bc);
    baseCorr[i0 + tid] = bc;
  }
  if (tid == 64){
    float a = 0.0f, b2 = 0.0f;
    for (int j = 0; j < 64; ++j){ a += ss[j]; b2 = fmaf(ss[j], cs[j], b2); }
    blkS0[b] = a; blkS0C[b] = b2;
  }
}

// ---- U[b][l] = sum_j s0[i0+j] * x[l][i0+j]
__global__ void k_u(const unsigned long long* __restrict__ xbits, const float* __restrict__ s0,
                    float* __restrict__ U){
  __shared__ float s0l[64];
  int b = blockIdx.x, l = threadIdx.x;  // 512 threads
  if (l < 64) s0l[l] = s0[b*64 + l];
  __syncthreads();
  unsigned long long w = xbits[(size_t)l*64 + b];
  unsigned int lo = (unsigned)w, hi = (unsigned)(w >> 32);
  unsigned int nlo = ~lo, nhi = ~hi;
  float acc = 0.0f;
  #pragma unroll
  for (int j = 0; j < 32; ++j){
    unsigned int m = (nlo << (31-j)) & 0x80000000u;
    acc += __uint_as_float(__float_as_uint(s0l[j]) ^ m);
  }
  #pragma unroll
  for (int j = 0; j < 32; ++j){
    unsigned int m = (nhi << (31-j)) & 0x80000000u;
    acc += __uint_as_float(__float_as_uint(s0l[32+j]) ^ m);
  }
  U[(size_t)b*512 + l] = acc;
}

// ---- p0[l] = sum_j sign(llv[l,j]) * s0[j]
__global__ void k_pinit(const float* __restrict__ llv, const float* __restrict__ s0,
                        float* __restrict__ p0){
  int l = blockIdx.x, lane = threadIdx.x;
  float acc = 0.0f;
  for (int c = 0; c < 64; ++c){
    float v = llv[(size_t)l*4096 + c*64 + lane];
    float sg = (v >= 0.0f) ? 1.0f : -1.0f;
    acc = fmaf(sg, s0[c*64 + lane], acc);
  }
  float tot = wave_allsum(acc);
  if (lane == 0) p0[l] = tot;
}

// ---- chain helpers (K from LDS, ping-pong b128 chunks) ----
#define STP(KVAL, J) { \
  int vi_ = __builtin_amdgcn_readlane(__float_as_int(v), (J)); \
  float sg2_ = (vi_ < 0) ? -1.0f : 1.0f; \
  sg_ |= ((unsigned long long)((~((unsigned)vi_)) >> 31)) << (J); \
  v = fmaf(sg2_, (KVAL), v); }
#define STP4(Q, J0) STP(Q.x,(J0)+0) STP(Q.y,(J0)+1) STP(Q.z,(J0)+2) STP(Q.w,(J0)+3)
#define LDK4(P, F0) { P##0 = Kp[((F0)+0)^sw]; P##1 = Kp[((F0)+1)^sw]; \
                      P##2 = Kp[((F0)+2)^sw]; P##3 = Kp[((F0)+3)^sw]; }
#define PROC16(P, J0) STP4(P##0,(J0)) STP4(P##1,(J0)+4) STP4(P##2,(J0)+8) STP4(P##3,(J0)+12)

// phase-1 accumulate one float component (bit JS of word W selects sign)
#define ACC1(F, W, JS) { \
  unsigned int m_ = ((~(W)) << (31-(JS))) & 0x80000000u; \
  acc += __uint_as_float(__float_as_uint(F) ^ m_); }

// ---- the sweep: 1 block, 512 threads, LDS-resident working set
__global__ __launch_bounds__(512, 1)
void k_sweep3(const unsigned long long* __restrict__ colbitsP,
              const unsigned long long* __restrict__ xbitsW,
              const float* __restrict__ Kf, const float* __restrict__ baseCorr,
              const float* __restrict__ blkS0, const float* __restrict__ blkS0C,
              const float* __restrict__ U, const float4* __restrict__ cst,
              const float* __restrict__ p0, const float* __restrict__ s0,
              const float* __restrict__ hdr, unsigned long long* __restrict__ sbits)
{
  __shared__ float Kl[2][64][64];                 // 32 KB (f4-swizzled rows)
  __shared__ unsigned long long cbl[2][8][64];    // 8 KB
  __shared__ unsigned long long xbl[2][512];      // 8 KB
  __shared__ float Ul[2][512];                    // 4 KB
  __shared__ float4 cstl[2][64];                  // 2 KB
  __shared__ float bcl[2][64];                    // 0.5 KB
  __shared__ float bs0l[64], bscl[64];            // 0.5 KB
  __shared__ float p[512];
  __shared__ float part[8][64];
  __shared__ float red[512];
  __shared__ unsigned long long sig;

  int tid = threadIdx.x, g = tid >> 6, t = tid & 63;
  float rho = hdr[0];

  // prologue: p, P, T init + tiny per-block scalars staged once
  p[tid] = p0[tid];
  red[tid] = p0[tid];
  if (tid < 64){ bs0l[tid] = blkS0[tid]; bscl[tid] = blkS0C[tid]; }
  __syncthreads();
  for (int st = 256; st > 0; st >>= 1){ if (tid < st) red[tid] += red[tid+st]; __syncthreads(); }
  float Preg = red[0];
  __syncthreads();
  { float a = 0.0f; for (int k = 0; k < 8; ++k) a += s0[tid*8 + k]; red[tid] = a; }
  __syncthreads();
  for (int st = 256; st > 0; st >>= 1){ if (tid < st) red[tid] += red[tid+st]; __syncthreads(); }
  float Treg = red[0];
  __syncthreads();

  for (int grp = 0; grp < 32; ++grp){
    // ---- stage group (blocks 2*grp, 2*grp+1) into LDS, coalesced ----
    {
      const float4* Ks = (const float4*)(Kf + (size_t)grp*8192);   // 2048 float4
      #pragma unroll
      for (int k = 0; k < 4; ++k){
        int e = tid + k*512;
        float4 vv = Ks[e];
        int gie = e >> 10, row = (e >> 4) & 63, f = e & 15;
        *((float4*)&Kl[gie][row][0] + (f ^ (row & 15))) = vv;      // swizzled store
      }
      #pragma unroll
      for (int k = 0; k < 2; ++k){
        int e = tid + k*512;                                       // 1024 u64
        int run = e >> 6, tt = e & 63, gie = run >> 3, wl = run & 7;
        cbl[gie][wl][tt] = colbitsP[(size_t)wl*4096 + (grp*2+gie)*64 + tt];
      }
      const unsigned long long* xs = xbitsW + (size_t)grp*1024;
      #pragma unroll
      for (int k = 0; k < 2; ++k){
        int e = tid + k*512;
        ((unsigned long long*)xbl)[e] = xs[e];
      }
      const float* Us = U + (size_t)grp*1024;
      #pragma unroll
      for (int k = 0; k < 2; ++k){
        int e = tid + k*512;
        ((float*)Ul)[e] = Us[e];
      }
      if (tid < 128){
        ((float4*)cstl)[tid] = cst[grp*128 + tid];
        ((float*)bcl)[tid]   = baseCorr[grp*128 + tid];
      }
    }
    __syncthreads();                               // staging done

    #pragma unroll
    for (int gi = 0; gi < 2; ++gi){
      int b = grp*2 + gi;
      // ---- phase 1: S partials (all LDS; j-ascending order = prior rounds) ----
      {
        unsigned long long w = cbl[gi][g][t];
        unsigned int lo = (unsigned)w, hi = (unsigned)(w >> 32);
        const float4* pw = (const float4*)(p + g*64);
        float acc = 0.0f;
        #pragma unroll
        for (int f = 0; f < 16; ++f){
          float4 q = pw[f];
          if (f < 8){
            ACC1(q.x, lo, 4*f+0) ACC1(q.y, lo, 4*f+1)
            ACC1(q.z, lo, 4*f+2) ACC1(q.w, lo, 4*f+3)
          } else {
            ACC1(q.x, hi, 4*f-32) ACC1(q.y, hi, 4*f-31)
            ACC1(q.z, hi, 4*f-30) ACC1(q.w, hi, 4*f-29)
          }
        }
        part[g][t] = acc;
      }
      __syncthreads();                             // B1

      if (g == 0){
        const float4* Kp = (const float4*)&Kl[gi][t][0];
        int sw = t & 15;
        float4 KA0,KA1,KA2,KA3, KB0,KB1,KB2,KB3;
        LDK4(KA, 0); LDK4(KB, 4);
        float S = 0.0f;
        #pragma unroll
        for (int gg = 0; gg < 8; ++gg) S += part[gg][t];
        float4 cc = cstl[gi][t];
        float bc_ = bcl[gi][t];
        float v = S - cc.x - rho*Preg - cc.y*Treg - bc_;
        unsigned long long sg_ = 0ull;
        PROC16(KA, 0);  LDK4(KA, 8);
        PROC16(KB, 16); LDK4(KB, 12);
        PROC16(KA, 32);
        PROC16(KB, 48);
        if (t == 0){ sig = sg_; sbits[b] = sg_; }
        float sv = ((sg_ >> t) & 1ull) ? cc.w : -cc.w;
        float sc = wave_allsum(sv);
        int pcs = __popcll(sg_);
        Preg += sc - bscl[b];
        Treg += (float)(2*pcs - 64) - bs0l[b];
      }
      __syncthreads();                             // B2
      // ---- phase 3: p update (all LDS) ----
      {
        unsigned long long sgv = sig;
        int pc = __popcll(xbl[gi][tid] ^ sgv);
        p[tid] = p[tid] + (float)(64 - 2*pc) - Ul[gi][tid];
      }
      __syncthreads();                             // B3
    }
  }
}

// ---- exact integer scores + argmax one-hot
__global__ void k_scores(const unsigned long long* __restrict__ xbits,
                         const unsigned long long* __restrict__ sbits,
                         float* __restrict__ out){
  __shared__ unsigned long long sb[64];
  __shared__ int bestkey;
  int tid = threadIdx.x;  // 512
  if (tid < 64) sb[tid] = sbits[tid];
  if (tid == 0) bestkey = -1;
  __syncthreads();
  int acc = 0;
  #pragma unroll
  for (int w = 0; w < 64; ++w)
    acc += __popcll(xbits[(size_t)tid*64 + w] ^ sb[w]);
  int dot = 4096 - 2*acc;
  int ad  = dot < 0 ? -dot : dot;
  int key = (ad << 10) | (511 - tid);
  atomicMax(&bestkey, key);
  __syncthreads();
  int bl = 511 - (bestkey & 1023);
  float val = (float)(bestkey >> 10) * (1.0f/4096.0f);
  out[tid] = (tid == bl) ? val : 0.0f;
}

extern "C" void kernel_launch(void* const* d_in, const int* in_sizes, int n_in,
                              void* d_out, int out_size, void* d_ws, size_t ws_size,
                              hipStream_t stream){
  const float* s0  = (const float*)d_in[0];   // [4096]
  const float* llv = (const float*)d_in[1];   // [512][4096]
  float* out = (float*)d_out;                 // [512]
  char* ws = (char*)d_ws;

  unsigned long long* colbitsP = (unsigned long long*)(ws + OFF_COLB);
  unsigned long long* xbits    = (unsigned long long*)(ws + OFF_XBITS);
  unsigned long long* xbitsW   = (unsigned long long*)(ws + OFF_XBW);
  float*  Kf    = (float*)(ws + OFF_KF);
  float*  bcorr = (float*)(ws + OFF_BCORR);
  float*  U     = (float*)(ws + OFF_U);
  float4* cst   = (float4*)(ws + OFF_CST);
  float*  p0    = (float*)(ws + OFF_P0);
  unsigned long long* sbits = (unsigned long long*)(ws + OFF_SBITS);
  int*    colcnt = (int*)(ws + OFF_CNT);
  float*  hdr   = (float*)(ws + OFF_HDR);
  float*  bS0   = (float*)(ws + OFF_BS0);
  float*  bS0C  = (float*)(ws + OFF_BS0C);

  k_xbits<<<128, 256, 0, stream>>>(llv, xbits, xbitsW);
  k_bitT<<<dim3(8, 64), 64, 0, stream>>>(xbits, colbitsP);
  k_colc<<<16, 256, 0, stream>>>(colbitsP, colcnt);
  k_rho<<<1, 256, 0, stream>>>(colcnt, hdr);
  k_const<<<16, 256, 0, stream>>>(colcnt, hdr, s0, cst);
  k_kdiag<<<64, 256, 0, stream>>>(colbitsP, cst, s0, hdr, Kf, bcorr, bS0, bS0C);
  k_u<<<64, 512, 0, stream>>>(xbits, s0, U);
  k_pinit<<<512, 64, 0, stream>>>(llv, s0, p0);
  k_sweep3<<<1, 512, 0, stream>>>(colbitsP, xbitsW, Kf, bcorr, bS0, bS0C, U, cst, p0, s0, hdr, sbits);
  k_scores<<<1, 512, 0, stream>>>(xbits, sbits, out);
}